// Round 2
// baseline (827.215 us; speedup 1.0000x reference)
//
#include <hip/hip_runtime.h>
#include <hip/hip_bf16.h>
#include <stdint.h>

typedef __bf16 bf16_t;
typedef bf16_t bf16x8 __attribute__((ext_vector_type(8)));
typedef bf16_t bf16x4 __attribute__((ext_vector_type(4)));
typedef float f32x4 __attribute__((ext_vector_type(4)));

#define B_ 2
#define Q_ 1024
#define PAST_ 1024
#define T_ 2048
#define HID_ 4096
#define NH_ 32
#define NKV_ 8
#define HD_ 128
#define SCALE_ 0.08838834764831845f

__device__ __forceinline__ void async_cp16(const bf16_t* g, bf16_t* l) {
  __builtin_amdgcn_global_load_lds((__attribute__((address_space(1))) void*)g,
                                   (__attribute__((address_space(3))) void*)l, 16, 0, 0);
}

// ---------------- fp32 -> bf16 convert (8 elems/thread) ----------------
__global__ void cvt_f32_bf16(const float* __restrict__ src, bf16_t* __restrict__ dst, size_t n) {
  size_t i = ((size_t)blockIdx.x * blockDim.x + threadIdx.x) * 8;
  if (i >= n) return;
  float4 a = *(const float4*)(src + i);
  float4 b = *(const float4*)(src + i + 4);
  bf16x8 o;
  o[0] = (bf16_t)a.x; o[1] = (bf16_t)a.y; o[2] = (bf16_t)a.z; o[3] = (bf16_t)a.w;
  o[4] = (bf16_t)b.x; o[5] = (bf16_t)b.y; o[6] = (bf16_t)b.z; o[7] = (bf16_t)b.w;
  *(bf16x8*)(dst + i) = o;
}

// ---------------- past KV copy: fp32 -> d_out, bf16 -> cache ----------------
__global__ void copy_past(const float* __restrict__ pk, const float* __restrict__ pv,
                          float* __restrict__ oK, float* __restrict__ oV,
                          bf16_t* __restrict__ Kall, bf16_t* __restrict__ Vall) {
  size_t i = ((size_t)blockIdx.x * 256 + threadIdx.x) * 4;
  if (i >= (size_t)B_ * NKV_ * PAST_ * HD_) return;
  int d = (int)(i & 127);
  size_t r = i >> 7;
  int t = (int)(r & 1023); r >>= 10;
  int g = (int)(r & 7); int b = (int)(r >> 3);
  size_t dst = (((size_t)b * NKV_ + g) * T_ + t) * HD_ + d;
  float4 k4 = *(const float4*)(pk + i);
  float4 v4 = *(const float4*)(pv + i);
  *(float4*)(oK + dst) = k4;
  *(float4*)(oV + dst) = v4;
  bf16x4 kb; kb[0] = (bf16_t)k4.x; kb[1] = (bf16_t)k4.y; kb[2] = (bf16_t)k4.z; kb[3] = (bf16_t)k4.w;
  bf16x4 vb; vb[0] = (bf16_t)v4.x; vb[1] = (bf16_t)v4.y; vb[2] = (bf16_t)v4.z; vb[3] = (bf16_t)v4.w;
  *(bf16x4*)(Kall + dst) = kb;
  *(bf16x4*)(Vall + dst) = vb;
}

// ---------------- GEMM: C[M,N] = A[M,K] @ W[N,K]^T, bf16 in, fp32 out ----------------
// 128x128 tile, BK=64, 4 waves each 64x64 (4x4 frags of 16x16x32 MFMA)
__global__ __launch_bounds__(256)
void gemm_bt(const bf16_t* __restrict__ A, const bf16_t* __restrict__ W,
             float* __restrict__ C, int M, int N, int K) {
  __shared__ bf16_t lA[128 * 64];
  __shared__ bf16_t lB[128 * 64];
  const int tid = threadIdx.x;
  const int wave = tid >> 6, lane = tid & 63;
  const int quad = lane >> 4, l15 = lane & 15;
  const int bm = blockIdx.y * 128, bn = blockIdx.x * 128;
  const int wm = (wave >> 1) * 64, wn = (wave & 1) * 64;
  f32x4 acc[4][4] = {};
  for (int k0 = 0; k0 < K; k0 += 64) {
    __syncthreads();
#pragma unroll
    for (int t = 0; t < 4; ++t) {
      int cb = t * 256 + wave * 64;
      int c = cb + lane;
      int row = c >> 3, col = (c & 7) << 3;
      async_cp16(A + (size_t)(bm + row) * K + k0 + col, lA + (size_t)cb * 8);
      async_cp16(W + (size_t)(bn + row) * K + k0 + col, lB + (size_t)cb * 8);
    }
    __syncthreads();
#pragma unroll
    for (int ks = 0; ks < 2; ++ks) {
      bf16x8 af[4], bfr[4];
      int kb = ks * 32 + quad * 8;
#pragma unroll
      for (int i = 0; i < 4; ++i) af[i] = *(const bf16x8*)(lA + (wm + i * 16 + l15) * 64 + kb);
#pragma unroll
      for (int j = 0; j < 4; ++j) bfr[j] = *(const bf16x8*)(lB + (wn + j * 16 + l15) * 64 + kb);
#pragma unroll
      for (int i = 0; i < 4; ++i)
#pragma unroll
        for (int j = 0; j < 4; ++j)
          acc[i][j] = __builtin_amdgcn_mfma_f32_16x16x32_bf16(af[i], bfr[j], acc[i][j], 0, 0, 0);
    }
  }
#pragma unroll
  for (int i = 0; i < 4; ++i) {
    int row0 = bm + wm + i * 16 + quad * 4;
#pragma unroll
    for (int j = 0; j < 4; ++j) {
      int col = bn + wn + j * 16 + l15;
#pragma unroll
      for (int r = 0; r < 4; ++r)
        C[(size_t)(row0 + r) * N + col] = acc[i][j][r];
    }
  }
}

// ---------------- RoPE + scatter ----------------
__global__ void rope_scatter(const float* __restrict__ QKV, const float* __restrict__ cosf,
                             const float* __restrict__ sinf, const int* __restrict__ pos_ids,
                             bf16_t* __restrict__ Qr, bf16_t* __restrict__ Kall,
                             bf16_t* __restrict__ Vall,
                             float* __restrict__ outK, float* __restrict__ outV) {
  int m = blockIdx.x;
  int b = m >> 10, s = m & 1023;
  int pos = pos_ids[(size_t)b * Q_ + s];  // int32 per harness contract
  const float* row = QKV + (size_t)m * 6144;
  int tid = threadIdx.x;
  for (int p = tid; p < NH_ * 64; p += 256) {
    int h = p >> 6, d = p & 63;
    float x1 = row[h * 128 + d], x2 = row[h * 128 + d + 64];
    float c = cosf[pos * 64 + d], sn = sinf[pos * 64 + d];
    size_t qb = (((size_t)b * NH_ + h) * Q_ + s) * HD_;
    Qr[qb + d] = (bf16_t)(x1 * c - x2 * sn);
    Qr[qb + d + 64] = (bf16_t)(x2 * c + x1 * sn);
  }
  for (int p = tid; p < NKV_ * 64; p += 256) {
    int g = p >> 6, d = p & 63;
    float x1 = row[4096 + g * 128 + d], x2 = row[4096 + g * 128 + d + 64];
    float c = cosf[pos * 64 + d], sn = sinf[pos * 64 + d];
    float o1 = x1 * c - x2 * sn, o2 = x2 * c + x1 * sn;
    size_t kbi = (((size_t)b * NKV_ + g) * T_ + PAST_ + s) * HD_;
    Kall[kbi + d] = (bf16_t)o1; Kall[kbi + d + 64] = (bf16_t)o2;
    outK[kbi + d] = o1; outK[kbi + d + 64] = o2;
  }
  for (int e = tid; e < NKV_ * HD_; e += 256) {
    int g = e >> 7, d = e & 127;
    float v = row[5120 + g * 128 + d];
    size_t vbi = (((size_t)b * NKV_ + g) * T_ + PAST_ + s) * HD_ + d;
    Vall[vbi] = (bf16_t)v;
    outV[vbi] = v;
  }
}

// ---------------- flash attention ----------------
// grid (Q/64, NH, B), 256 threads. Wave w: q rows qbase + w*16 .. +16
__global__ __launch_bounds__(256)
void attn_fwd(const bf16_t* __restrict__ Qr, const bf16_t* __restrict__ Kall,
              const bf16_t* __restrict__ Vall, bf16_t* __restrict__ Ctx) {
  __shared__ bf16_t lK[64 * 128];
  __shared__ bf16_t lVt[128 * 64];
  __shared__ bf16_t lP[4 * 16 * 64];
  const int tid = threadIdx.x;
  const int wave = tid >> 6, lane = tid & 63;
  const int quad = lane >> 4, l15 = lane & 15;
  const int qt = blockIdx.x, h = blockIdx.y, b = blockIdx.z;
  const int kv = h >> 2;
  const int qbase = qt * 64;
  const size_t kvbase = ((size_t)b * NKV_ + kv) * T_ * HD_;
  const bf16_t* qg = Qr + ((((size_t)b * NH_ + h) * Q_) + qbase + wave * 16 + l15) * HD_ + quad * 8;
  bf16x8 qf[4];
#pragma unroll
  for (int kk = 0; kk < 4; ++kk) qf[kk] = *(const bf16x8*)(qg + kk * 32);
  f32x4 ctx[8] = {};
  float Mr[4], Lr[4];
#pragma unroll
  for (int r = 0; r < 4; ++r) { Mr[r] = -3.0e30f; Lr[r] = 0.0f; }
  const int prow0 = PAST_ + qbase + wave * 16 + quad * 4;
  bf16_t* lPw = lP + wave * 16 * 64;
  const int kend = PAST_ + qbase + 64;
  for (int kb = 0; kb < kend; kb += 64) {
    __syncthreads();
    // stage K tile (64 keys x 128), row-major, via async DMA
#pragma unroll
    for (int t = 0; t < 4; ++t) {
      int cb = t * 256 + wave * 64;
      int c = cb + lane;
      int row = c >> 4, col = (c & 15) << 3;
      async_cp16(Kall + kvbase + (size_t)(kb + row) * HD_ + col, lK + (size_t)cb * 8);
    }
    // stage V transposed (hd x keys)
    {
      int k = tid & 63, dbase = (tid >> 6) * 32;
      const bf16_t* vg = Vall + kvbase + (size_t)(kb + k) * HD_ + dbase;
      bf16x8 vv[4];
#pragma unroll
      for (int q8 = 0; q8 < 4; ++q8) vv[q8] = *(const bf16x8*)(vg + q8 * 8);
#pragma unroll
      for (int q8 = 0; q8 < 4; ++q8)
#pragma unroll
        for (int j = 0; j < 8; ++j)
          lVt[(dbase + q8 * 8 + j) * 64 + k] = vv[q8][j];
    }
    __syncthreads();
    // S = Q K^T  (16 q-rows x 64 keys per wave)
    f32x4 sacc[4];
#pragma unroll
    for (int nc = 0; nc < 4; ++nc) {
      f32x4 z = {0.0f, 0.0f, 0.0f, 0.0f};
#pragma unroll
      for (int kk = 0; kk < 4; ++kk) {
        bf16x8 bk = *(const bf16x8*)(lK + (nc * 16 + l15) * 128 + kk * 32 + quad * 8);
        z = __builtin_amdgcn_mfma_f32_16x16x32_bf16(qf[kk], bk, z, 0, 0, 0);
      }
      sacc[nc] = z;
    }
    // online softmax
    float sv[4][4], tm[4], alpha[4], rs[4];
#pragma unroll
    for (int r = 0; r < 4; ++r) tm[r] = -3.0e30f;
#pragma unroll
    for (int nc = 0; nc < 4; ++nc) {
      int tkey = kb + nc * 16 + l15;
#pragma unroll
      for (int r = 0; r < 4; ++r) {
        float val = sacc[nc][r] * SCALE_ + ((tkey > prow0 + r) ? -10000.0f : 0.0f);
        sv[nc][r] = val;
        tm[r] = fmaxf(tm[r], val);
      }
    }
#pragma unroll
    for (int r = 0; r < 4; ++r) {
#pragma unroll
      for (int mm = 1; mm < 16; mm <<= 1) tm[r] = fmaxf(tm[r], __shfl_xor(tm[r], mm, 64));
      float nm = fmaxf(Mr[r], tm[r]);
      alpha[r] = __expf(Mr[r] - nm);
      Mr[r] = nm;
      rs[r] = 0.0f;
    }
#pragma unroll
    for (int nc = 0; nc < 4; ++nc)
#pragma unroll
      for (int r = 0; r < 4; ++r) {
        float p = __expf(sv[nc][r] - Mr[r]);
        rs[r] += p;
        lPw[(quad * 4 + r) * 64 + nc * 16 + l15] = (bf16_t)p;
      }
#pragma unroll
    for (int r = 0; r < 4; ++r) {
#pragma unroll
      for (int mm = 1; mm < 16; mm <<= 1) rs[r] += __shfl_xor(rs[r], mm, 64);
      Lr[r] = Lr[r] * alpha[r] + rs[r];
    }
#pragma unroll
    for (int nc2 = 0; nc2 < 8; ++nc2)
#pragma unroll
      for (int r = 0; r < 4; ++r) ctx[nc2][r] *= alpha[r];
    asm volatile("s_waitcnt lgkmcnt(0)" ::: "memory");
    // ctx += P @ V
#pragma unroll
    for (int kk2 = 0; kk2 < 2; ++kk2) {
      bf16x8 ap = *(const bf16x8*)(lPw + l15 * 64 + kk2 * 32 + quad * 8);
#pragma unroll
      for (int nc2 = 0; nc2 < 8; ++nc2) {
        bf16x8 bv = *(const bf16x8*)(lVt + (nc2 * 16 + l15) * 64 + kk2 * 32 + quad * 8);
        ctx[nc2] = __builtin_amdgcn_mfma_f32_16x16x32_bf16(ap, bv, ctx[nc2], 0, 0, 0);
      }
    }
  }
  float inv[4];
#pragma unroll
  for (int r = 0; r < 4; ++r) inv[r] = 1.0f / Lr[r];
#pragma unroll
  for (int nc2 = 0; nc2 < 8; ++nc2)
#pragma unroll
    for (int r = 0; r < 4; ++r) {
      size_t row = (size_t)b * Q_ + qbase + wave * 16 + quad * 4 + r;
      Ctx[row * (NH_ * HD_) + h * HD_ + nc2 * 16 + l15] = (bf16_t)(ctx[nc2][r] * inv[r]);
    }
}

extern "C" void kernel_launch(void* const* d_in, const int* in_sizes, int n_in,
                              void* d_out, int out_size, void* d_ws, size_t ws_size,
                              hipStream_t stream) {
  const float* hidden = (const float*)d_in[0];
  const int* pos = (const int*)d_in[2];
  const float* cosf = (const float*)d_in[3];
  const float* sinf = (const float*)d_in[4];
  const float* past_k = (const float*)d_in[5];
  const float* past_v = (const float*)d_in[6];
  const float* q_w = (const float*)d_in[7];
  const float* k_w = (const float*)d_in[8];
  const float* v_w = (const float*)d_in[9];
  const float* o_w = (const float*)d_in[10];

  float* attn_out = (float*)d_out;
  float* outK = attn_out + (size_t)B_ * Q_ * HID_;
  float* outV = outK + (size_t)B_ * NKV_ * T_ * HD_;

  // workspace layout (144 MiB total, with aliasing):
  //   Wqkv : [0, 48M)        6144x4096 bf16
  //   Xb   : [48M, 64M)      2048x4096 bf16   (consumed by gemm1)
  //   QKV  : [64M, 112M)     2048x6144 fp32   (consumed by rope_scatter)
  //   Qr   : [112M, 128M)    (B,NH,Q,HD) bf16
  //   Kall : [128M, 136M)    (B,NKV,T,HD) bf16
  //   Vall : [136M, 144M)    (B,NKV,T,HD) bf16
  //   Wo   : aliases QKV     4096x4096 bf16   (converted after rope_scatter)
  //   Ctx  : aliases Xb      2048x4096 bf16   (written after gemm1)
  if (ws_size < 150994944) return;
  char* ws = (char*)d_ws;
  bf16_t* Wqkv = (bf16_t*)(ws);
  bf16_t* Xb   = (bf16_t*)(ws + 50331648);
  float*  QKV  = (float*)(ws + 67108864);
  bf16_t* Qr   = (bf16_t*)(ws + 117440512);
  bf16_t* Kall = (bf16_t*)(ws + 134217728);
  bf16_t* Vall = (bf16_t*)(ws + 142606336);
  bf16_t* Wo   = (bf16_t*)(ws + 67108864);   // alias QKV
  bf16_t* Ctx  = (bf16_t*)(ws + 50331648);   // alias Xb

  cvt_f32_bf16<<<4096, 256, 0, stream>>>(hidden, Xb, 8388608);
  cvt_f32_bf16<<<8192, 256, 0, stream>>>(q_w, Wqkv, 16777216);
  cvt_f32_bf16<<<2048, 256, 0, stream>>>(k_w, Wqkv + 16777216, 4194304);
  cvt_f32_bf16<<<2048, 256, 0, stream>>>(v_w, Wqkv + 20971520, 4194304);
  copy_past<<<2048, 256, 0, stream>>>(past_k, past_v, outK, outV, Kall, Vall);
  gemm_bt<<<dim3(48, 16), 256, 0, stream>>>(Xb, Wqkv, QKV, 2048, 6144, 4096);
  rope_scatter<<<2048, 256, 0, stream>>>(QKV, cosf, sinf, pos, Qr, Kall, Vall, outK, outV);
  cvt_f32_bf16<<<8192, 256, 0, stream>>>(o_w, Wo, 16777216);  // after QKV consumed
  attn_fwd<<<dim3(16, 32, 2), 256, 0, stream>>>(Qr, Kall, Vall, Ctx);
  gemm_bt<<<dim3(32, 16), 256, 0, stream>>>(Ctx, Wo, attn_out, 2048, 4096, 4096);
}

// Round 3
// 710.890 us; speedup vs baseline: 1.1636x; 1.1636x over previous
//
#include <hip/hip_runtime.h>
#include <hip/hip_bf16.h>
#include <stdint.h>

typedef __bf16 bf16_t;
typedef bf16_t bf16x8 __attribute__((ext_vector_type(8)));
typedef bf16_t bf16x4 __attribute__((ext_vector_type(4)));
typedef float f32x4 __attribute__((ext_vector_type(4)));

#define B_ 2
#define Q_ 1024
#define PAST_ 1024
#define T_ 2048
#define HID_ 4096
#define NH_ 32
#define NKV_ 8
#define HD_ 128
#define SCALE_ 0.08838834764831845f

__device__ __forceinline__ void async_cp16(const bf16_t* g, bf16_t* l) {
  __builtin_amdgcn_global_load_lds((__attribute__((address_space(1))) void*)g,
                                   (__attribute__((address_space(3))) void*)l, 16, 0, 0);
}

// ---------------- fp32 -> bf16 convert (8 elems/thread) ----------------
__global__ void cvt_f32_bf16(const float* __restrict__ src, bf16_t* __restrict__ dst, size_t n) {
  size_t i = ((size_t)blockIdx.x * blockDim.x + threadIdx.x) * 8;
  if (i >= n) return;
  float4 a = *(const float4*)(src + i);
  float4 b = *(const float4*)(src + i + 4);
  bf16x8 o;
  o[0] = (bf16_t)a.x; o[1] = (bf16_t)a.y; o[2] = (bf16_t)a.z; o[3] = (bf16_t)a.w;
  o[4] = (bf16_t)b.x; o[5] = (bf16_t)b.y; o[6] = (bf16_t)b.z; o[7] = (bf16_t)b.w;
  *(bf16x8*)(dst + i) = o;
}

// ---------------- past KV copy: fp32 -> d_out, bf16 -> cache ----------------
__global__ void copy_past(const float* __restrict__ pk, const float* __restrict__ pv,
                          float* __restrict__ oK, float* __restrict__ oV,
                          bf16_t* __restrict__ Kall, bf16_t* __restrict__ Vall) {
  size_t i = ((size_t)blockIdx.x * 256 + threadIdx.x) * 4;
  if (i >= (size_t)B_ * NKV_ * PAST_ * HD_) return;
  int d = (int)(i & 127);
  size_t r = i >> 7;
  int t = (int)(r & 1023); r >>= 10;
  int g = (int)(r & 7); int b = (int)(r >> 3);
  size_t dst = (((size_t)b * NKV_ + g) * T_ + t) * HD_ + d;
  float4 k4 = *(const float4*)(pk + i);
  float4 v4 = *(const float4*)(pv + i);
  *(float4*)(oK + dst) = k4;
  *(float4*)(oV + dst) = v4;
  bf16x4 kb; kb[0] = (bf16_t)k4.x; kb[1] = (bf16_t)k4.y; kb[2] = (bf16_t)k4.z; kb[3] = (bf16_t)k4.w;
  bf16x4 vb; vb[0] = (bf16_t)v4.x; vb[1] = (bf16_t)v4.y; vb[2] = (bf16_t)v4.z; vb[3] = (bf16_t)v4.w;
  *(bf16x4*)(Kall + dst) = kb;
  *(bf16x4*)(Vall + dst) = vb;
}

// ---------------- GEMM: C[M,N] = A[M,K] @ W[N,K]^T, bf16 in, fp32 out ----------------
// 128x128 tile, BK=64. XOR-swizzled LDS chunks: logical chunk c of row r lives at
// slot c^(r&7); staging permutes the SOURCE column so global_load_lds dst stays
// lane-contiguous. Fragment reads then spread over banks (2-way = free).
__global__ __launch_bounds__(256)
void gemm_bt(const bf16_t* __restrict__ A, const bf16_t* __restrict__ W,
             float* __restrict__ C, int M, int N, int K) {
  __shared__ bf16_t lA[128 * 64];
  __shared__ bf16_t lB[128 * 64];
  const int tid = threadIdx.x;
  const int wave = tid >> 6, lane = tid & 63;
  const int quad = lane >> 4, l15 = lane & 15;
  const int bm = blockIdx.y * 128, bn = blockIdx.x * 128;
  const int wm = (wave >> 1) * 64, wn = (wave & 1) * 64;
  f32x4 acc[4][4] = {};
  for (int k0 = 0; k0 < K; k0 += 64) {
    __syncthreads();
#pragma unroll
    for (int t = 0; t < 4; ++t) {
      int cb = t * 256 + wave * 64;
      int c = cb + lane;
      int row = c >> 3, sc = (c & 7) ^ (row & 7);
      async_cp16(A + (size_t)(bm + row) * K + k0 + sc * 8, lA + (size_t)cb * 8);
      async_cp16(W + (size_t)(bn + row) * K + k0 + sc * 8, lB + (size_t)cb * 8);
    }
    __syncthreads();
#pragma unroll
    for (int ks = 0; ks < 2; ++ks) {
      bf16x8 af[4], bfr[4];
      int lchunk = ks * 4 + quad;
      int pc = (lchunk ^ (l15 & 7)) * 8;
#pragma unroll
      for (int i = 0; i < 4; ++i) af[i] = *(const bf16x8*)(lA + (wm + i * 16 + l15) * 64 + pc);
#pragma unroll
      for (int j = 0; j < 4; ++j) bfr[j] = *(const bf16x8*)(lB + (wn + j * 16 + l15) * 64 + pc);
#pragma unroll
      for (int i = 0; i < 4; ++i)
#pragma unroll
        for (int j = 0; j < 4; ++j)
          acc[i][j] = __builtin_amdgcn_mfma_f32_16x16x32_bf16(af[i], bfr[j], acc[i][j], 0, 0, 0);
    }
  }
#pragma unroll
  for (int i = 0; i < 4; ++i) {
    int row0 = bm + wm + i * 16 + quad * 4;
#pragma unroll
    for (int j = 0; j < 4; ++j) {
      int col = bn + wn + j * 16 + l15;
#pragma unroll
      for (int r = 0; r < 4; ++r)
        C[(size_t)(row0 + r) * N + col] = acc[i][j][r];
    }
  }
}

// ---------------- RoPE + scatter ----------------
__global__ void rope_scatter(const float* __restrict__ QKV, const float* __restrict__ cosf,
                             const float* __restrict__ sinf, const int* __restrict__ pos_ids,
                             bf16_t* __restrict__ Qr, bf16_t* __restrict__ Kall,
                             bf16_t* __restrict__ Vall,
                             float* __restrict__ outK, float* __restrict__ outV) {
  int m = blockIdx.x;
  int b = m >> 10, s = m & 1023;
  int pos = pos_ids[(size_t)b * Q_ + s];
  const float* row = QKV + (size_t)m * 6144;
  int tid = threadIdx.x;
  for (int p = tid; p < NH_ * 64; p += 256) {
    int h = p >> 6, d = p & 63;
    float x1 = row[h * 128 + d], x2 = row[h * 128 + d + 64];
    float c = cosf[pos * 64 + d], sn = sinf[pos * 64 + d];
    size_t qb = (((size_t)b * NH_ + h) * Q_ + s) * HD_;
    Qr[qb + d] = (bf16_t)(x1 * c - x2 * sn);
    Qr[qb + d + 64] = (bf16_t)(x2 * c + x1 * sn);
  }
  for (int p = tid; p < NKV_ * 64; p += 256) {
    int g = p >> 6, d = p & 63;
    float x1 = row[4096 + g * 128 + d], x2 = row[4096 + g * 128 + d + 64];
    float c = cosf[pos * 64 + d], sn = sinf[pos * 64 + d];
    float o1 = x1 * c - x2 * sn, o2 = x2 * c + x1 * sn;
    size_t kbi = (((size_t)b * NKV_ + g) * T_ + PAST_ + s) * HD_;
    Kall[kbi + d] = (bf16_t)o1; Kall[kbi + d + 64] = (bf16_t)o2;
    outK[kbi + d] = o1; outK[kbi + d + 64] = o2;
  }
  for (int e = tid; e < NKV_ * HD_; e += 256) {
    int g = e >> 7, d = e & 127;
    float v = row[5120 + g * 128 + d];
    size_t vbi = (((size_t)b * NKV_ + g) * T_ + PAST_ + s) * HD_ + d;
    Vall[vbi] = (bf16_t)v;
    outV[vbi] = v;
  }
}

// ---------------- flash attention ----------------
// grid (Q/128, NH, B), 256 threads. Wave w owns q rows qbase+w*32 .. +32 (2 m-frags).
// LDS: lK 64x128 (16-chunk XOR swizzle), lVt transposed V padded to stride 72,
// lP per-wave P staging padded to stride 72. Total 52 KB -> 3 blocks/CU.
#define VS 72
__global__ __launch_bounds__(256, 3)
void attn_fwd(const bf16_t* __restrict__ Qr, const bf16_t* __restrict__ Kall,
              const bf16_t* __restrict__ Vall, bf16_t* __restrict__ Ctx) {
  __shared__ bf16_t lK[64 * 128];
  __shared__ bf16_t lVt[128 * VS];
  __shared__ bf16_t lP[4 * 32 * VS];
  const int tid = threadIdx.x;
  const int wave = tid >> 6, lane = tid & 63;
  const int quad = lane >> 4, l15 = lane & 15;
  const int qt = blockIdx.x, h = blockIdx.y, b = blockIdx.z;
  const int kv = h >> 2;
  const int qbase = qt * 128;
  const int wq = qbase + wave * 32;
  const size_t kvbase = ((size_t)b * NKV_ + kv) * T_ * HD_;
  // Q fragments: 2 m-frags x 4 k-chunks
  bf16x8 qf[2][4];
#pragma unroll
  for (int mi = 0; mi < 2; ++mi) {
    const bf16_t* qg = Qr + ((((size_t)b * NH_ + h) * Q_) + wq + mi * 16 + l15) * HD_ + quad * 8;
#pragma unroll
    for (int kk = 0; kk < 4; ++kk) qf[mi][kk] = *(const bf16x8*)(qg + kk * 32);
  }
  f32x4 ctx[2][8] = {};
  float Mr[2][4], Lr[2][4];
#pragma unroll
  for (int mi = 0; mi < 2; ++mi)
#pragma unroll
    for (int r = 0; r < 4; ++r) { Mr[mi][r] = -3.0e30f; Lr[mi][r] = 0.0f; }
  bf16_t* lPw = lP + wave * 32 * VS;
  const int kend = PAST_ + qbase + 128;
  const int wlimit = PAST_ + wq + 31;  // last key this wave's rows can see
  for (int kb = 0; kb < kend; kb += 64) {
    __syncthreads();
    // stage K tile (64 keys x 128), chunk-XOR swizzled
#pragma unroll
    for (int t = 0; t < 4; ++t) {
      int cb = t * 256 + wave * 64;
      int c = cb + lane;
      int row = c >> 4, sc = (c & 15) ^ (row & 15);
      async_cp16(Kall + kvbase + (size_t)(kb + row) * HD_ + sc * 8, lK + (size_t)cb * 8);
    }
    // stage V transposed (padded stride VS): lanes write contiguous 128B rows
    {
      int key = lane, dbase = wave * 32;
      const bf16_t* vg = Vall + kvbase + (size_t)(kb + key) * HD_ + dbase;
      bf16x8 vv[4];
#pragma unroll
      for (int q8 = 0; q8 < 4; ++q8) vv[q8] = *(const bf16x8*)(vg + q8 * 8);
#pragma unroll
      for (int q8 = 0; q8 < 4; ++q8)
#pragma unroll
        for (int j = 0; j < 8; ++j)
          lVt[(dbase + q8 * 8 + j) * VS + key] = vv[q8][j];
    }
    __syncthreads();
    if (kb <= wlimit) {
      // S = Q K^T : 2 m-frags x 64 keys
      f32x4 sacc[2][4];
#pragma unroll
      for (int mi = 0; mi < 2; ++mi)
#pragma unroll
        for (int nc = 0; nc < 4; ++nc) sacc[mi][nc] = (f32x4){0.f, 0.f, 0.f, 0.f};
#pragma unroll
      for (int nc = 0; nc < 4; ++nc)
#pragma unroll
        for (int kk = 0; kk < 4; ++kk) {
          bf16x8 bk = *(const bf16x8*)(lK + (nc * 16 + l15) * 128 + (((kk * 4 + quad) ^ l15) << 3));
#pragma unroll
          for (int mi = 0; mi < 2; ++mi)
            sacc[mi][nc] = __builtin_amdgcn_mfma_f32_16x16x32_bf16(qf[mi][kk], bk, sacc[mi][nc], 0, 0, 0);
        }
      // scale + mask
      bool fullvis = (kb + 63 <= PAST_ + wq);
#pragma unroll
      for (int mi = 0; mi < 2; ++mi)
#pragma unroll
        for (int nc = 0; nc < 4; ++nc) {
          int tkey = kb + nc * 16 + l15;
#pragma unroll
          for (int r = 0; r < 4; ++r) {
            float val = sacc[mi][nc][r] * SCALE_;
            if (!fullvis) {
              int row_abs = PAST_ + wq + mi * 16 + quad * 4 + r;
              if (tkey > row_abs) val -= 10000.0f;
            }
            sacc[mi][nc][r] = val;
          }
        }
      // online softmax
      float alpha[2][4];
#pragma unroll
      for (int mi = 0; mi < 2; ++mi)
#pragma unroll
        for (int r = 0; r < 4; ++r) {
          float tm = fmaxf(fmaxf(sacc[mi][0][r], sacc[mi][1][r]), fmaxf(sacc[mi][2][r], sacc[mi][3][r]));
#pragma unroll
          for (int mmk = 1; mmk < 16; mmk <<= 1) tm = fmaxf(tm, __shfl_xor(tm, mmk, 64));
          float nm = fmaxf(Mr[mi][r], tm);
          alpha[mi][r] = __expf(Mr[mi][r] - nm);
          Mr[mi][r] = nm;
        }
      float rs[2][4] = {};
#pragma unroll
      for (int mi = 0; mi < 2; ++mi)
#pragma unroll
        for (int nc = 0; nc < 4; ++nc)
#pragma unroll
          for (int r = 0; r < 4; ++r) {
            float p = __expf(sacc[mi][nc][r] - Mr[mi][r]);
            rs[mi][r] += p;
            lPw[(mi * 16 + quad * 4 + r) * VS + nc * 16 + l15] = (bf16_t)p;
          }
#pragma unroll
      for (int mi = 0; mi < 2; ++mi)
#pragma unroll
        for (int r = 0; r < 4; ++r) {
          float s = rs[mi][r];
#pragma unroll
          for (int mmk = 1; mmk < 16; mmk <<= 1) s += __shfl_xor(s, mmk, 64);
          Lr[mi][r] = Lr[mi][r] * alpha[mi][r] + s;
        }
#pragma unroll
      for (int mi = 0; mi < 2; ++mi)
#pragma unroll
        for (int nc2 = 0; nc2 < 8; ++nc2)
#pragma unroll
          for (int r = 0; r < 4; ++r) ctx[mi][nc2][r] *= alpha[mi][r];
      asm volatile("s_waitcnt lgkmcnt(0)" ::: "memory");
      // ctx += P @ V
#pragma unroll
      for (int kk2 = 0; kk2 < 2; ++kk2) {
        bf16x8 ap[2];
#pragma unroll
        for (int mi = 0; mi < 2; ++mi)
          ap[mi] = *(const bf16x8*)(lPw + (mi * 16 + l15) * VS + kk2 * 32 + quad * 8);
#pragma unroll
        for (int nc2 = 0; nc2 < 8; ++nc2) {
          bf16x8 bv = *(const bf16x8*)(lVt + (nc2 * 16 + l15) * VS + kk2 * 32 + quad * 8);
#pragma unroll
          for (int mi = 0; mi < 2; ++mi)
            ctx[mi][nc2] = __builtin_amdgcn_mfma_f32_16x16x32_bf16(ap[mi], bv, ctx[mi][nc2], 0, 0, 0);
        }
      }
    }
  }
  // epilogue
#pragma unroll
  for (int mi = 0; mi < 2; ++mi) {
    float inv[4];
#pragma unroll
    for (int r = 0; r < 4; ++r) inv[r] = 1.0f / Lr[mi][r];
#pragma unroll
    for (int nc2 = 0; nc2 < 8; ++nc2)
#pragma unroll
      for (int r = 0; r < 4; ++r) {
        size_t row = (size_t)b * Q_ + wq + mi * 16 + quad * 4 + r;
        Ctx[row * (NH_ * HD_) + h * HD_ + nc2 * 16 + l15] = (bf16_t)(ctx[mi][nc2][r] * inv[r]);
      }
  }
}

extern "C" void kernel_launch(void* const* d_in, const int* in_sizes, int n_in,
                              void* d_out, int out_size, void* d_ws, size_t ws_size,
                              hipStream_t stream) {
  const float* hidden = (const float*)d_in[0];
  const int* pos = (const int*)d_in[2];
  const float* cosf = (const float*)d_in[3];
  const float* sinf = (const float*)d_in[4];
  const float* past_k = (const float*)d_in[5];
  const float* past_v = (const float*)d_in[6];
  const float* q_w = (const float*)d_in[7];
  const float* k_w = (const float*)d_in[8];
  const float* v_w = (const float*)d_in[9];
  const float* o_w = (const float*)d_in[10];

  float* attn_out = (float*)d_out;
  float* outK = attn_out + (size_t)B_ * Q_ * HID_;
  float* outV = outK + (size_t)B_ * NKV_ * T_ * HD_;

  if (ws_size < 150994944) return;
  char* ws = (char*)d_ws;
  bf16_t* Wqkv = (bf16_t*)(ws);
  bf16_t* Xb   = (bf16_t*)(ws + 50331648);
  float*  QKV  = (float*)(ws + 67108864);
  bf16_t* Qr   = (bf16_t*)(ws + 117440512);
  bf16_t* Kall = (bf16_t*)(ws + 134217728);
  bf16_t* Vall = (bf16_t*)(ws + 142606336);
  bf16_t* Wo   = (bf16_t*)(ws + 67108864);   // alias QKV (converted after rope)
  bf16_t* Ctx  = (bf16_t*)(ws + 50331648);   // alias Xb (written after gemm1)

  cvt_f32_bf16<<<4096, 256, 0, stream>>>(hidden, Xb, 8388608);
  cvt_f32_bf16<<<8192, 256, 0, stream>>>(q_w, Wqkv, 16777216);
  cvt_f32_bf16<<<2048, 256, 0, stream>>>(k_w, Wqkv + 16777216, 4194304);
  cvt_f32_bf16<<<2048, 256, 0, stream>>>(v_w, Wqkv + 20971520, 4194304);
  copy_past<<<2048, 256, 0, stream>>>(past_k, past_v, outK, outV, Kall, Vall);
  gemm_bt<<<dim3(48, 16), 256, 0, stream>>>(Xb, Wqkv, QKV, 2048, 6144, 4096);
  rope_scatter<<<2048, 256, 0, stream>>>(QKV, cosf, sinf, pos, Qr, Kall, Vall, outK, outV);
  cvt_f32_bf16<<<8192, 256, 0, stream>>>(o_w, Wo, 16777216);
  attn_fwd<<<dim3(8, 32, 2), 256, 0, stream>>>(Qr, Kall, Vall, Ctx);
  gemm_bt<<<dim3(32, 16), 256, 0, stream>>>(Ctx, Wo, attn_out, 2048, 4096, 4096);
}

// Round 4
// 616.823 us; speedup vs baseline: 1.3411x; 1.1525x over previous
//
#include <hip/hip_runtime.h>
#include <hip/hip_bf16.h>
#include <stdint.h>

typedef __bf16 bf16_t;
typedef bf16_t bf16x8 __attribute__((ext_vector_type(8)));
typedef bf16_t bf16x4 __attribute__((ext_vector_type(4)));
typedef float f32x4 __attribute__((ext_vector_type(4)));

#define B_ 2
#define Q_ 1024
#define PAST_ 1024
#define T_ 2048
#define HID_ 4096
#define NH_ 32
#define NKV_ 8
#define HD_ 128
#define SCALE_ 0.08838834764831845f

__device__ __forceinline__ void async_cp16(const bf16_t* g, bf16_t* l) {
  __builtin_amdgcn_global_load_lds((__attribute__((address_space(1))) void*)g,
                                   (__attribute__((address_space(3))) void*)l, 16, 0, 0);
}

// ---------------- fp32 -> bf16 convert (8 elems/thread) ----------------
__global__ void cvt_f32_bf16(const float* __restrict__ src, bf16_t* __restrict__ dst, size_t n) {
  size_t i = ((size_t)blockIdx.x * blockDim.x + threadIdx.x) * 8;
  if (i >= n) return;
  float4 a = *(const float4*)(src + i);
  float4 b = *(const float4*)(src + i + 4);
  bf16x8 o;
  o[0] = (bf16_t)a.x; o[1] = (bf16_t)a.y; o[2] = (bf16_t)a.z; o[3] = (bf16_t)a.w;
  o[4] = (bf16_t)b.x; o[5] = (bf16_t)b.y; o[6] = (bf16_t)b.z; o[7] = (bf16_t)b.w;
  *(bf16x8*)(dst + i) = o;
}

// ---------------- past KV copy: fp32 -> d_out, bf16 K -> cache ----------------
__global__ void copy_past(const float* __restrict__ pk, const float* __restrict__ pv,
                          float* __restrict__ oK, float* __restrict__ oV,
                          bf16_t* __restrict__ Kall) {
  size_t i = ((size_t)blockIdx.x * 256 + threadIdx.x) * 4;
  if (i >= (size_t)B_ * NKV_ * PAST_ * HD_) return;
  int d = (int)(i & 127);
  size_t r = i >> 7;
  int t = (int)(r & 1023); r >>= 10;
  int g = (int)(r & 7); int b = (int)(r >> 3);
  size_t dst = (((size_t)b * NKV_ + g) * T_ + t) * HD_ + d;
  float4 k4 = *(const float4*)(pk + i);
  float4 v4 = *(const float4*)(pv + i);
  *(float4*)(oK + dst) = k4;
  *(float4*)(oV + dst) = v4;
  bf16x4 kb; kb[0] = (bf16_t)k4.x; kb[1] = (bf16_t)k4.y; kb[2] = (bf16_t)k4.z; kb[3] = (bf16_t)k4.w;
  *(bf16x4*)(Kall + dst) = kb;
}

// ---------------- build transposed V cache: Vt[b][g][d][t] bf16 ----------------
// grid (T/64, NKV, B), 256 thr. Source: past_v for t<PAST, QKV V-section else.
__global__ void build_vt(const float* __restrict__ past_v, const float* __restrict__ QKV,
                         bf16_t* __restrict__ Vt) {
  __shared__ bf16_t tile[64][136];
  const int tid = threadIdx.x;
  const int t0 = blockIdx.x * 64, g = blockIdx.y, b = blockIdx.z;
#pragma unroll
  for (int k = 0; k < 8; ++k) {
    int idx = k * 256 + tid;            // 0..2047 : (t, 4-col chunk)
    int t = idx >> 5, dc = (idx & 31) * 4;
    int tt = t0 + t;
    const float* src = (tt < PAST_)
        ? past_v + ((((size_t)b * NKV_ + g) * PAST_ + tt) * HD_ + dc)
        : QKV + (((size_t)b * Q_ + (tt - PAST_)) * 6144 + 5120 + g * HD_ + dc);
    float4 v4 = *(const float4*)src;
    tile[t][dc] = (bf16_t)v4.x; tile[t][dc + 1] = (bf16_t)v4.y;
    tile[t][dc + 2] = (bf16_t)v4.z; tile[t][dc + 3] = (bf16_t)v4.w;
  }
  __syncthreads();
#pragma unroll
  for (int k = 0; k < 4; ++k) {
    int idx = k * 256 + tid;            // 0..1023 : (d, 8-key chunk)
    int d = idx >> 3, c = idx & 7;
    bf16x8 o;
#pragma unroll
    for (int j = 0; j < 8; ++j) o[j] = tile[c * 8 + j][d];
    *(bf16x8*)(Vt + ((((size_t)b * NKV_ + g) * HD_ + d) * T_) + t0 + c * 8) = o;
  }
}

// ---------------- GEMM: C[M,N] = A[M,K] @ W[N,K]^T, bf16 in, fp32 out ----------------
__global__ __launch_bounds__(256)
void gemm_bt(const bf16_t* __restrict__ A, const bf16_t* __restrict__ W,
             float* __restrict__ C, int M, int N, int K) {
  __shared__ bf16_t lA[128 * 64];
  __shared__ bf16_t lB[128 * 64];
  const int tid = threadIdx.x;
  const int wave = tid >> 6, lane = tid & 63;
  const int quad = lane >> 4, l15 = lane & 15;
  const int bm = blockIdx.y * 128, bn = blockIdx.x * 128;
  const int wm = (wave >> 1) * 64, wn = (wave & 1) * 64;
  f32x4 acc[4][4] = {};
  for (int k0 = 0; k0 < K; k0 += 64) {
    __syncthreads();
#pragma unroll
    for (int t = 0; t < 4; ++t) {
      int cb = t * 256 + wave * 64;
      int c = cb + lane;
      int row = c >> 3, sc = (c & 7) ^ (row & 7);
      async_cp16(A + (size_t)(bm + row) * K + k0 + sc * 8, lA + (size_t)cb * 8);
      async_cp16(W + (size_t)(bn + row) * K + k0 + sc * 8, lB + (size_t)cb * 8);
    }
    __syncthreads();
#pragma unroll
    for (int ks = 0; ks < 2; ++ks) {
      bf16x8 af[4], bfr[4];
      int lchunk = ks * 4 + quad;
      int pc = (lchunk ^ (l15 & 7)) * 8;
#pragma unroll
      for (int i = 0; i < 4; ++i) af[i] = *(const bf16x8*)(lA + (wm + i * 16 + l15) * 64 + pc);
#pragma unroll
      for (int j = 0; j < 4; ++j) bfr[j] = *(const bf16x8*)(lB + (wn + j * 16 + l15) * 64 + pc);
#pragma unroll
      for (int i = 0; i < 4; ++i)
#pragma unroll
        for (int j = 0; j < 4; ++j)
          acc[i][j] = __builtin_amdgcn_mfma_f32_16x16x32_bf16(af[i], bfr[j], acc[i][j], 0, 0, 0);
    }
  }
#pragma unroll
  for (int i = 0; i < 4; ++i) {
    int row0 = bm + wm + i * 16 + quad * 4;
#pragma unroll
    for (int j = 0; j < 4; ++j) {
      int col = bn + wn + j * 16 + l15;
#pragma unroll
      for (int r = 0; r < 4; ++r)
        C[(size_t)(row0 + r) * N + col] = acc[i][j][r];
    }
  }
}

// ---------------- RoPE + scatter (Q bf16 head-major; new K rows; fp32 K,V outs) ------
__global__ void rope_scatter(const float* __restrict__ QKV, const float* __restrict__ cosf,
                             const float* __restrict__ sinf, const int* __restrict__ pos_ids,
                             bf16_t* __restrict__ Qr, bf16_t* __restrict__ Kall,
                             float* __restrict__ outK, float* __restrict__ outV) {
  int m = blockIdx.x;
  int b = m >> 10, s = m & 1023;
  int pos = pos_ids[(size_t)b * Q_ + s];
  const float* row = QKV + (size_t)m * 6144;
  int tid = threadIdx.x;
  for (int p = tid; p < NH_ * 64; p += 256) {
    int h = p >> 6, d = p & 63;
    float x1 = row[h * 128 + d], x2 = row[h * 128 + d + 64];
    float c = cosf[pos * 64 + d], sn = sinf[pos * 64 + d];
    size_t qb = (((size_t)b * NH_ + h) * Q_ + s) * HD_;
    Qr[qb + d] = (bf16_t)(x1 * c - x2 * sn);
    Qr[qb + d + 64] = (bf16_t)(x2 * c + x1 * sn);
  }
  for (int p = tid; p < NKV_ * 64; p += 256) {
    int g = p >> 6, d = p & 63;
    float x1 = row[4096 + g * 128 + d], x2 = row[4096 + g * 128 + d + 64];
    float c = cosf[pos * 64 + d], sn = sinf[pos * 64 + d];
    float o1 = x1 * c - x2 * sn, o2 = x2 * c + x1 * sn;
    size_t kbi = (((size_t)b * NKV_ + g) * T_ + PAST_ + s) * HD_;
    Kall[kbi + d] = (bf16_t)o1; Kall[kbi + d + 64] = (bf16_t)o2;
    outK[kbi + d] = o1; outK[kbi + d + 64] = o2;
  }
  for (int e = tid; e < NKV_ * HD_; e += 256) {
    int g = e >> 7, d = e & 127;
    float v = row[5120 + g * 128 + d];
    outV[(((size_t)b * NKV_ + g) * T_ + PAST_ + s) * HD_ + d] = v;
  }
}

// ---------------- flash attention ----------------
// 1-D grid 1024 blocks, 256 thr. XCD swizzle: all blocks of a (b,kv) pair share
// one XCD (L2 locality); heavy q-tiles dispatched first. Wave owns 16 q-rows.
// LDS: lK 64keys x 128d (16B-chunk XOR swizzle), lV 128d x 64keys (XOR swizzle,
// staged straight from transposed-V global), lP per-wave 16x64 (XOR swizzle).
// Total 40960 B -> 4 blocks/CU.
__global__ __launch_bounds__(256, 4)
void attn_fwd(const bf16_t* __restrict__ Qr, const bf16_t* __restrict__ Kall,
              const bf16_t* __restrict__ Vt, bf16_t* __restrict__ Ctx) {
  __shared__ bf16_t lK[64 * 128];
  __shared__ bf16_t lV[128 * 64];
  __shared__ bf16_t lP[4 * 16 * 64];
  const int tid = threadIdx.x;
  const int wave = tid >> 6, lane = tid & 63;
  const int quad = lane >> 4, l15 = lane & 15;
  // XCD-aware decode
  const int i = blockIdx.x;
  const int xcd = i & 7;
  const int j = i >> 3;
  const int pairsel = j & 1;
  const int idx = j >> 1;          // 0..63
  const int h_in = idx & 3;
  const int qt = 15 - (idx >> 2);  // heavy first
  const int b = pairsel, kv = xcd;
  const int h = kv * 4 + h_in;
  const int qbase = qt * 64;
  const int wq = qbase + wave * 16;
  const size_t kvbase = ((size_t)b * NKV_ + kv) * T_ * HD_;  // Kall
  const size_t vtbase = ((size_t)b * NKV_ + kv) * HD_ * T_;  // Vt (d-major)
  bf16x8 qf[4];
  {
    const bf16_t* qg = Qr + ((((size_t)b * NH_ + h) * Q_) + wq + l15) * HD_ + quad * 8;
#pragma unroll
    for (int kk = 0; kk < 4; ++kk) qf[kk] = *(const bf16x8*)(qg + kk * 32);
  }
  f32x4 ctx[8] = {};
  float Mr[4], Lr[4];
#pragma unroll
  for (int r = 0; r < 4; ++r) { Mr[r] = -3.0e30f; Lr[r] = 0.0f; }
  bf16_t* lPw = lP + wave * 16 * 64;
  const int kend = PAST_ + qbase + 64;
  const int wlimit = PAST_ + wq + 15;
  for (int kb = 0; kb < kend; kb += 64) {
    __syncthreads();
    // stage K tile: 64 keys x 128 d, 16B chunks XOR-swizzled by key row
#pragma unroll
    for (int t = 0; t < 4; ++t) {
      int cb = t * 256 + wave * 64;
      int c = cb + lane;
      int row = c >> 4, sc = (c & 15) ^ (row & 15);
      async_cp16(Kall + kvbase + (size_t)(kb + row) * HD_ + sc * 8, lK + (size_t)cb * 8);
    }
    // stage V tile from Vt: 128 d-rows x 64 keys, 16B chunks XOR-swizzled by d row
#pragma unroll
    for (int t = 0; t < 4; ++t) {
      int cb = t * 256 + wave * 64;
      int c = cb + lane;
      int d = c >> 3, sc = (c & 7) ^ (d & 7);
      async_cp16(Vt + vtbase + (size_t)d * T_ + kb + sc * 8, lV + (size_t)cb * 8);
    }
    __syncthreads();
    if (kb <= wlimit) {
      // S = Q K^T : 16 q-rows x 64 keys
      f32x4 sacc[4];
#pragma unroll
      for (int nc = 0; nc < 4; ++nc) sacc[nc] = (f32x4){0.f, 0.f, 0.f, 0.f};
#pragma unroll
      for (int nc = 0; nc < 4; ++nc)
#pragma unroll
        for (int kk = 0; kk < 4; ++kk) {
          bf16x8 bk = *(const bf16x8*)(lK + (nc * 16 + l15) * 128 + (((kk * 4 + quad) ^ l15) << 3));
          sacc[nc] = __builtin_amdgcn_mfma_f32_16x16x32_bf16(qf[kk], bk, sacc[nc], 0, 0, 0);
        }
      // scale + causal mask
      bool fullvis = (kb + 63 <= PAST_ + wq);
#pragma unroll
      for (int nc = 0; nc < 4; ++nc) {
        int tkey = kb + nc * 16 + l15;
#pragma unroll
        for (int r = 0; r < 4; ++r) {
          float val = sacc[nc][r] * SCALE_;
          if (!fullvis && tkey > PAST_ + wq + quad * 4 + r) val -= 10000.0f;
          sacc[nc][r] = val;
        }
      }
      // online softmax
      float alpha[4], rs[4] = {};
#pragma unroll
      for (int r = 0; r < 4; ++r) {
        float tm = fmaxf(fmaxf(sacc[0][r], sacc[1][r]), fmaxf(sacc[2][r], sacc[3][r]));
#pragma unroll
        for (int mmk = 1; mmk < 16; mmk <<= 1) tm = fmaxf(tm, __shfl_xor(tm, mmk, 64));
        float nm = fmaxf(Mr[r], tm);
        alpha[r] = __expf(Mr[r] - nm);
        Mr[r] = nm;
      }
#pragma unroll
      for (int nc = 0; nc < 4; ++nc)
#pragma unroll
        for (int r = 0; r < 4; ++r) {
          float p = __expf(sacc[nc][r] - Mr[r]);
          rs[r] += p;
          int rho = quad * 4 + r;
          int cslot = ((nc * 2 + (l15 >> 3)) ^ (rho & 7));
          lPw[rho * 64 + cslot * 8 + (l15 & 7)] = (bf16_t)p;
        }
#pragma unroll
      for (int r = 0; r < 4; ++r) {
        float s = rs[r];
#pragma unroll
        for (int mmk = 1; mmk < 16; mmk <<= 1) s += __shfl_xor(s, mmk, 64);
        Lr[r] = Lr[r] * alpha[r] + s;
      }
#pragma unroll
      for (int nc2 = 0; nc2 < 8; ++nc2)
#pragma unroll
        for (int r = 0; r < 4; ++r) ctx[nc2][r] *= alpha[r];
      asm volatile("s_waitcnt lgkmcnt(0)" ::: "memory");
      // ctx += P @ V
#pragma unroll
      for (int kk2 = 0; kk2 < 2; ++kk2) {
        bf16x8 ap = *(const bf16x8*)(lPw + l15 * 64 + (((kk2 * 4 + quad) ^ (l15 & 7)) << 3));
#pragma unroll
        for (int nc2 = 0; nc2 < 8; ++nc2) {
          bf16x8 bv = *(const bf16x8*)(lV + (nc2 * 16 + l15) * 64 + (((kk2 * 4 + quad) ^ (l15 & 7)) << 3));
          ctx[nc2] = __builtin_amdgcn_mfma_f32_16x16x32_bf16(ap, bv, ctx[nc2], 0, 0, 0);
        }
      }
    }
  }
  float inv[4];
#pragma unroll
  for (int r = 0; r < 4; ++r) inv[r] = 1.0f / Lr[r];
#pragma unroll
  for (int nc2 = 0; nc2 < 8; ++nc2)
#pragma unroll
    for (int r = 0; r < 4; ++r) {
      size_t row = (size_t)b * Q_ + wq + quad * 4 + r;
      Ctx[row * (NH_ * HD_) + h * HD_ + nc2 * 16 + l15] = (bf16_t)(ctx[nc2][r] * inv[r]);
    }
}

extern "C" void kernel_launch(void* const* d_in, const int* in_sizes, int n_in,
                              void* d_out, int out_size, void* d_ws, size_t ws_size,
                              hipStream_t stream) {
  const float* hidden = (const float*)d_in[0];
  const int* pos = (const int*)d_in[2];
  const float* cosf = (const float*)d_in[3];
  const float* sinf = (const float*)d_in[4];
  const float* past_k = (const float*)d_in[5];
  const float* past_v = (const float*)d_in[6];
  const float* q_w = (const float*)d_in[7];
  const float* k_w = (const float*)d_in[8];
  const float* v_w = (const float*)d_in[9];
  const float* o_w = (const float*)d_in[10];

  float* attn_out = (float*)d_out;
  float* outK = attn_out + (size_t)B_ * Q_ * HID_;
  float* outV = outK + (size_t)B_ * NKV_ * T_ * HD_;

  if (ws_size < 150994944) return;
  char* ws = (char*)d_ws;
  bf16_t* Wqkv = (bf16_t*)(ws);              // 48 MiB
  bf16_t* Xb   = (bf16_t*)(ws + 50331648);   // 16 MiB
  float*  QKV  = (float*)(ws + 67108864);    // 48 MiB
  bf16_t* Qr   = (bf16_t*)(ws + 117440512);  // 16 MiB
  bf16_t* Kall = (bf16_t*)(ws + 134217728);  // 8 MiB
  bf16_t* Vt   = (bf16_t*)(ws + 142606336);  // 8 MiB (d-major transposed V)
  bf16_t* Wo   = (bf16_t*)(ws + 67108864);   // alias QKV (converted after build_vt)
  bf16_t* Ctx  = (bf16_t*)(ws + 50331648);   // alias Xb (written after gemm1)

  cvt_f32_bf16<<<4096, 256, 0, stream>>>(hidden, Xb, 8388608);
  cvt_f32_bf16<<<8192, 256, 0, stream>>>(q_w, Wqkv, 16777216);
  cvt_f32_bf16<<<2048, 256, 0, stream>>>(k_w, Wqkv + 16777216, 4194304);
  cvt_f32_bf16<<<2048, 256, 0, stream>>>(v_w, Wqkv + 20971520, 4194304);
  copy_past<<<2048, 256, 0, stream>>>(past_k, past_v, outK, outV, Kall);
  gemm_bt<<<dim3(48, 16), 256, 0, stream>>>(Xb, Wqkv, QKV, 2048, 6144, 4096);
  rope_scatter<<<2048, 256, 0, stream>>>(QKV, cosf, sinf, pos, Qr, Kall, outK, outV);
  build_vt<<<dim3(32, 8, 2), 256, 0, stream>>>(past_v, QKV, Vt);
  cvt_f32_bf16<<<8192, 256, 0, stream>>>(o_w, Wo, 16777216);  // after QKV consumed
  attn_fwd<<<1024, 256, 0, stream>>>(Qr, Kall, Vt, Ctx);
  gemm_bt<<<dim3(32, 16), 256, 0, stream>>>(Ctx, Wo, attn_out, 2048, 4096, 4096);
}